// Round 4
// baseline (438.024 us; speedup 1.0000x reference)
//
#include <hip/hip_runtime.h>

// GPT-2 block forward, MI355X/gfx950. B=4 T=2048 C=768 H=12 D=64; M=8192.
// R13 = R12 resubmitted (round-3 bench was an infra failure, kernel audited
// clean). GEMM: m97-shape with modern fixes:
//   - 128x128 tile, BK=64, 256 thr (2x2 waves, 64x64/wave)
//   - SINGLE 32 KiB LDS buffer, 2 barriers/K-tile -> 5 blocks/CU; overlap
//     across blocks hides the staging drain (m97/m114 evidence: single-buf
//     + multi-block > explicit pipeline at 1 block/CU)
//   - R11-proven XOR swizzle (pre-swizzled glds16 source + swizzled ds_read,
//     0 bank conflicts), XCD-locality 1D grid decode
// Attention: R11 (glds16 double-buffered K/V staging, 1 barrier/tile).

typedef unsigned short ushortT;
typedef unsigned int uintT;
typedef __attribute__((ext_vector_type(8))) __bf16 bf16x8;
typedef __attribute__((ext_vector_type(4))) float f32x4;

#define MFMA16(a, b, c) __builtin_amdgcn_mfma_f32_16x16x32_bf16(a, b, c, 0, 0, 0)

__device__ inline float b2f(ushortT u) {
  return __uint_as_float(((uintT)u) << 16);
}
__device__ inline ushortT f2b(float f) {  // round-to-nearest-even
  uintT x = __float_as_uint(f);
  uintT r = x + 0x7fffu + ((x >> 16) & 1u);
  return (ushortT)(r >> 16);
}
// pack two f32 -> two bf16 (RTZ) in one v_perm_b32
__device__ inline uintT pack_bf2(float a, float b) {
  return __builtin_amdgcn_perm(__float_as_uint(b), __float_as_uint(a),
                               0x07060302u);
}

__device__ inline float fast_exp2(float x) {
#if __has_builtin(__builtin_amdgcn_exp2f)
  return __builtin_amdgcn_exp2f(x);
#else
  return exp2f(x);
#endif
}

__device__ inline float gelu_tanh(float v) {
  float t = 0.7978845608028654f * (v + 0.044715f * v * v * v);
  return v / (1.0f + __expf(-2.0f * t));
}

// async 16B/lane global->LDS. LDS dest = wave-uniform base + lane*16.
__device__ __forceinline__ void glds16(const ushortT* g, ushortT* l) {
  __builtin_amdgcn_global_load_lds(
      (const __attribute__((address_space(1))) unsigned int*)(const void*)g,
      (__attribute__((address_space(3))) unsigned int*)(void*)l, 16, 0, 0);
}

// ------------------------------------------------------------- dtype detect
__global__ __launch_bounds__(256) void detect_dtype(
    const ushortT* __restrict__ w, int* __restrict__ flag) {
  __shared__ int red;
  if (threadIdx.x == 0) red = 0;
  __syncthreads();
  int crazy = 0;
  for (int i = threadIdx.x; i < 4096; i += 256) {
    uintT e = (w[2 * i] >> 7) & 0xFF;
    if (e >= 150) crazy = 1;
  }
  if (crazy) atomicOr(&red, 1);
  __syncthreads();
  if (threadIdx.x == 0) *flag = red;
}

// ------------------------------------------------------------- small vectors
struct VecArgs {
  const void* src[8];
  int n[8];
  int dstoff[8];
};
__global__ __launch_bounds__(256) void convert_vecs(
    VecArgs a, ushortT* __restrict__ pv, const int* __restrict__ flag) {
  int fl = *flag;
  int t = blockIdx.y;
  int i = blockIdx.x * 256 + threadIdx.x;
  if (i >= a.n[t]) return;
  float v = fl ? ((const float*)a.src[t])[i] : b2f(((const ushortT*)a.src[t])[i]);
  pv[a.dstoff[t] + i] = f2b(v);
}

// ---------------------------------------------------------------- transpose
__global__ __launch_bounds__(256) void transpose_any(
    const void* __restrict__ in, ushortT* __restrict__ out, int K, int N,
    const int* __restrict__ flag) {
  __shared__ ushortT t[32][33];
  int fl = *flag;
  int n0 = blockIdx.x * 32, k0 = blockIdx.y * 32;
  int x = threadIdx.x, y0 = threadIdx.y;
#pragma unroll
  for (int i = y0; i < 32; i += 8) {
    size_t idx = (size_t)(k0 + i) * N + n0 + x;
    t[i][x] = fl ? f2b(((const float*)in)[idx]) : ((const ushortT*)in)[idx];
  }
  __syncthreads();
#pragma unroll
  for (int i = y0; i < 32; i += 8)
    out[(size_t)(n0 + i) * K + k0 + x] = t[x][i];
}

// ------------------------------------------------------- V transpose (attn)
__global__ __launch_bounds__(256) void vtrans_kernel(
    const ushortT* __restrict__ qkv, ushortT* __restrict__ vt) {
  const int T = 2048, C3 = 2304;
  __shared__ ushortT tile[64][65];
  int bh = blockIdx.y;
  int b = bh / 12, h = bh % 12;
  int t0 = blockIdx.x * 64;
  int col = threadIdx.x & 63, rowi = threadIdx.x >> 6;
#pragma unroll
  for (int rr = rowi; rr < 64; rr += 4)
    tile[rr][col] =
        qkv[((size_t)(b * T + t0 + rr)) * C3 + 1536 + h * 64 + col];
  __syncthreads();
#pragma unroll
  for (int dd = rowi; dd < 64; dd += 4)
    vt[((size_t)bh * 64 + dd) * T + t0 + col] = tile[col][dd];
}

// ---------------------------------------------------------------- layernorm
template <int MODE>
__global__ __launch_bounds__(256) void ln_kernel(
    const void* __restrict__ xin, const ushortT* __restrict__ g,
    const ushortT* __restrict__ bb, ushortT* __restrict__ out,
    const int* __restrict__ flag) {
  const int C = 768;
  bool f32;
  if constexpr (MODE == 1) f32 = true; else f32 = (*flag != 0);
  size_t base = (size_t)blockIdx.x * C;
  int tid = threadIdx.x;
  const float* xf = (const float*)xin;
  const ushortT* xb = (const ushortT*)xin;
  float v0 = f32 ? xf[base + tid]       : b2f(xb[base + tid]);
  float v1 = f32 ? xf[base + tid + 256] : b2f(xb[base + tid + 256]);
  float v2 = f32 ? xf[base + tid + 512] : b2f(xb[base + tid + 512]);
  float s = v0 + v1 + v2;
  float q = v0 * v0 + v1 * v1 + v2 * v2;
#pragma unroll
  for (int off = 32; off; off >>= 1) {
    s += __shfl_xor(s, off);
    q += __shfl_xor(q, off);
  }
  __shared__ float as_[4], aq_[4];
  if ((tid & 63) == 0) { as_[tid >> 6] = s; aq_[tid >> 6] = q; }
  __syncthreads();
  s = as_[0] + as_[1] + as_[2] + as_[3];
  q = aq_[0] + aq_[1] + aq_[2] + aq_[3];
  float mu = s * (1.0f / 768.0f);
  float var = q * (1.0f / 768.0f) - mu * mu;
  float rs = rsqrtf(var + 1e-5f);
  ushortT* orow = out + base;
  orow[tid]       = f2b((v0 - mu) * rs * b2f(g[tid])       + b2f(bb[tid]));
  orow[tid + 256] = f2b((v1 - mu) * rs * b2f(g[tid + 256]) + b2f(bb[tid + 256]));
  orow[tid + 512] = f2b((v2 - mu) * rs * b2f(g[tid + 512]) + b2f(bb[tid + 512]));
}

// ---------------------------------------------------------------- GEMM
// C[M,N] = A[M,K] @ Bt[N,K]^T + bias. 128x128 tile, 256 thr (2x2 waves),
// BK=64, SINGLE 32 KiB LDS buffer, 2 barriers/K-tile -> 5 blocks/CU.
// LDS rows [128][64] bf16 (128B). XOR swizzle: stored slot s holds global
// col16 s^(row&7); staging source pre-swizzled, ds_read col quad^(n&7).
// EPI: 0 bias->bf16 | 1 bias+gelu->bf16 | 2 bias+res(flag dtype)->fp32
//      3 bias+res(fp32)->flag-dtype out
template <int EPI>
__global__ __launch_bounds__(256) void gemm_sb(
    const ushortT* __restrict__ A, const ushortT* __restrict__ Bt,
    const ushortT* __restrict__ bias, const void* __restrict__ res,
    void* __restrict__ out, int N, int K, int nbm, int nbn,
    const int* __restrict__ flag) {
  __shared__ ushortT As[128 * 64];  // 16 KiB
  __shared__ ushortT Bs[128 * 64];  // 16 KiB
  int fl = (EPI >= 2) ? *flag : 0;
  int tid = threadIdx.x;
  int lane = tid & 63, wave = tid >> 6;
  int quad = lane >> 4, n = lane & 15, n7 = n & 7;
  int wm = (wave >> 1) * 64, wn = (wave & 1) * 64;  // 2x2 wave grid
  // XCD-locality decode: all nbn n-blocks of one m-strip land on one XCD
  int l = blockIdx.x;
  int xcd = l & 7, j = l >> 3;
  int m0 = (xcd * (nbm >> 3) + j / nbn) * 128;
  int n0 = (j % nbn) * 128;

  // staging: thread -> row tid/8 within the 32-row sweep group, slot tid&7,
  // source col pre-swizzled so LDS stays linear.
  int trow = tid >> 3;
  int tc = ((tid & 7) ^ (trow & 7)) << 3;
  const ushortT* ga = A + (size_t)(m0 + trow) * K + tc;
  const ushortT* gb = Bt + (size_t)(n0 + trow) * K + tc;
  const int ldst = wave * 512;  // wave-uniform LDS dest base (elems)

  const int c0 = (quad ^ n7) << 3;
  const int c1 = ((4 + quad) ^ n7) << 3;
  const int arow = (wm + n) * 64;
  const int brow = (wn + n) * 64;

  f32x4 acc[4][4] = {};

  for (int k0 = 0; k0 < K; k0 += 64) {
    __syncthreads();  // prev tile's ds_reads complete before overwrite
#pragma unroll
    for (int i = 0; i < 4; ++i)
      glds16(ga + (size_t)(i * 32) * K + k0, As + ldst + i * 2048);
#pragma unroll
    for (int i = 0; i < 4; ++i)
      glds16(gb + (size_t)(i * 32) * K + k0, Bs + ldst + i * 2048);
    __syncthreads();  // vmcnt(0)+barrier: staged tile visible

    bf16x8 af[4][2], bfr[4][2];
#pragma unroll
    for (int mi = 0; mi < 4; ++mi) {
      af[mi][0] = *(const bf16x8*)(As + arow + mi * 1024 + c0);
      af[mi][1] = *(const bf16x8*)(As + arow + mi * 1024 + c1);
    }
#pragma unroll
    for (int ni = 0; ni < 4; ++ni) {
      bfr[ni][0] = *(const bf16x8*)(Bs + brow + ni * 1024 + c0);
      bfr[ni][1] = *(const bf16x8*)(Bs + brow + ni * 1024 + c1);
    }
#pragma unroll
    for (int mi = 0; mi < 4; ++mi)
#pragma unroll
      for (int ni = 0; ni < 4; ++ni) {
        acc[mi][ni] = MFMA16(af[mi][0], bfr[ni][0], acc[mi][ni]);
        acc[mi][ni] = MFMA16(af[mi][1], bfr[ni][1], acc[mi][ni]);
      }
  }

  // ---- epilogue
#pragma unroll
  for (int mi = 0; mi < 4; ++mi) {
#pragma unroll
    for (int ni = 0; ni < 4; ++ni) {
      int gc = n0 + wn + ni * 16 + n;
      float bv = b2f(bias[gc]);
      int gr0 = m0 + wm + mi * 16 + quad * 4;
#pragma unroll
      for (int r = 0; r < 4; ++r) {
        size_t idx = (size_t)(gr0 + r) * N + gc;
        float v = acc[mi][ni][r] + bv;
        if constexpr (EPI == 1) v = gelu_tanh(v);
        if constexpr (EPI == 2) {
          v += fl ? ((const float*)res)[idx] : b2f(((const ushortT*)res)[idx]);
          ((float*)out)[idx] = v;
        } else if constexpr (EPI == 3) {
          v += ((const float*)res)[idx];
          if (fl) ((float*)out)[idx] = v;
          else    ((ushortT*)out)[idx] = f2b(v);
        } else {
          ((ushortT*)out)[idx] = f2b(v);
        }
      }
    }
  }
}

// ---------------------------------------------------------------- attention
// Flash, causal, balanced (block pj does q-tiles pj and 31-pj = 33 k-tiles).
// 4 waves x 16 q-rows. S^T = K Q^T, O^T = V^T P^T. Fixed-offset base-2
// softmax. K/V staged via global_load_lds DMA into a double buffer with
// XOR-swizzled source cols (linear LDS dest); one __syncthreads per tile.
__global__ __launch_bounds__(256) void attn_kernel(
    const ushortT* __restrict__ qkv, const ushortT* __restrict__ vt,
    ushortT* __restrict__ y) {
  const int T = 2048, C3 = 2304;
  constexpr int LDP = 72;
  __shared__ ushortT Ks[2][64 * 64];
  __shared__ ushortT Vs[2][64 * 64];
  __shared__ ushortT Ps[4 * 16 * LDP];
  int bh = blockIdx.y;
  int b = bh / 12, h = bh % 12;
  int pj = blockIdx.x;  // 0..15
  int tid = threadIdx.x;
  int lane = tid & 63, wave = tid >> 6;
  int quad = lane >> 4, n = lane & 15, n7 = n & 7;

  const ushortT* base = qkv + (size_t)b * T * C3;
  const ushortT* kbase = base + 768 + h * 64;
  const ushortT* vbase = vt + (size_t)bh * 64 * T;
  ushortT* myP = Ps + wave * 16 * LDP;

  const float QS = 0.18033688011112042f;  // log2(e)/8
  const float MB = 20.0f;                 // fixed base-2 shift

  int qtA = pj, qtB = 31 - pj;
  int nA = qtA + 1, ntot = 33;

  int srow = lane >> 3, scol = lane & 7;
  const ushortT* kg =
      kbase + (size_t)(wave * 16 + srow) * C3 + ((scol ^ srow) << 3);
  const ushortT* vg =
      vbase + (size_t)(wave * 16 + srow) * T + ((scol ^ srow) << 3);

  const int c0 = (quad ^ n7) << 3;
  const int c1 = ((4 + quad) ^ n7) << 3;

  int qt = qtA;
  int qw = qt * 64 + wave * 16;
  bf16x8 aq[2];
  {
    const ushortT* qrow = base + (size_t)(qw + n) * C3 + h * 64 + quad * 8;
#pragma unroll
    for (int dh = 0; dh < 2; ++dh) {
      union { ushortT u[8]; bf16x8 v; } tmp;
#pragma unroll
      for (int j = 0; j < 8; ++j) tmp.u[j] = f2b(b2f(qrow[dh * 32 + j]) * QS);
      aq[dh] = tmp.v;
    }
  }
  f32x4 Ot[4] = {};
  float l_ = 0.f;

  auto stage = [&](int kt_, int buf) {
    int kof = kt_ << 6;
    ushortT* lk = &Ks[buf][0] + wave * 1024;
    ushortT* lv = &Vs[buf][0] + wave * 1024;
    glds16(kg + (size_t)kof * C3, lk);
    glds16(kg + (size_t)(kof + 8) * C3, lk + 512);
    glds16(vg + kof, lv);
    glds16(vg + (size_t)8 * T + kof, lv + 512);
  };

  stage(0, 0);
  __syncthreads();  // emits vmcnt(0): tile 0 landed

  int cur = 0;
  for (int t = 0; t < ntot; ++t) {
    int kt = (t < nA) ? t : t - nA;
    if (t + 1 < ntot) {
      int ktn = (t + 1 < nA) ? t + 1 : t + 1 - nA;
      stage(ktn, cur ^ 1);  // prefetch t+1 while computing t
    }
    const ushortT* ks = &Ks[cur][0];
    const ushortT* vs = &Vs[cur][0];

    // ---- S^T = K (Q*QS)^T  (base-2 units)
    f32x4 St[4];
#pragma unroll
    for (int g = 0; g < 4; ++g) {
      bf16x8 ka0 = *(const bf16x8*)(ks + (g * 16 + n) * 64 + c0);
      bf16x8 ka1 = *(const bf16x8*)(ks + (g * 16 + n) * 64 + c1);
      f32x4 z = {};
      z = MFMA16(ka0, aq[0], z);
      St[g] = MFMA16(ka1, aq[1], z);
    }
    // ---- diagonal-tile causal mask
    if (kt == qt) {
      int lim = wave * 16 + n;
#pragma unroll
      for (int g = 0; g < 4; ++g)
#pragma unroll
        for (int r = 0; r < 4; ++r)
          if (g * 16 + quad * 4 + r > lim) St[g][r] = -1e30f;
    }
    // ---- fixed-offset exp2, accumulate l
    float ls = 0.f;
#pragma unroll
    for (int g = 0; g < 4; ++g) {
      float p0 = fast_exp2(St[g][0] - MB);
      float p1 = fast_exp2(St[g][1] - MB);
      float p2 = fast_exp2(St[g][2] - MB);
      float p3 = fast_exp2(St[g][3] - MB);
      ls += (p0 + p1) + (p2 + p3);
      uint2 pk;
      pk.x = pack_bf2(p0, p1);
      pk.y = pack_bf2(p2, p3);
      *(uint2*)(myP + n * LDP + g * 16 + quad * 4) = pk;
    }
    ls += __shfl_xor(ls, 16);
    ls += __shfl_xor(ls, 32);
    l_ += ls;

    // ---- O^T += V^T P^T
    bf16x8 pb0 = *(const bf16x8*)(myP + n * LDP + quad * 8);
    bf16x8 pb1 = *(const bf16x8*)(myP + n * LDP + 32 + quad * 8);
#pragma unroll
    for (int dt = 0; dt < 4; ++dt) {
      bf16x8 va0 = *(const bf16x8*)(vs + (dt * 16 + n) * 64 + c0);
      bf16x8 va1 = *(const bf16x8*)(vs + (dt * 16 + n) * 64 + c1);
      Ot[dt] = MFMA16(va0, pb0, Ot[dt]);
      Ot[dt] = MFMA16(va1, pb1, Ot[dt]);
    }

    // ---- phase end: epilogue + reset for phase B
    if (kt == qt) {
      float inv = 1.0f / l_;
      int qg = qw + n;
#pragma unroll
      for (int dt = 0; dt < 4; ++dt) {
        uint2 o;
        o.x = pack_bf2(Ot[dt][0] * inv, Ot[dt][1] * inv);
        o.y = pack_bf2(Ot[dt][2] * inv, Ot[dt][3] * inv);
        *(uint2*)(y + (size_t)(b * T + qg) * 768 + h * 64 + dt * 16 +
                  quad * 4) = o;
      }
      if (t + 1 < ntot) {
        qt = qtB;
        qw = qt * 64 + wave * 16;
        const ushortT* qrow =
            base + (size_t)(qw + n) * C3 + h * 64 + quad * 8;
#pragma unroll
        for (int dh = 0; dh < 2; ++dh) {
          union { ushortT u[8]; bf16x8 v; } tmp;
#pragma unroll
          for (int j = 0; j < 8; ++j)
            tmp.u[j] = f2b(b2f(qrow[dh * 32 + j]) * QS);
          aq[dh] = tmp.v;
        }
#pragma unroll
        for (int dt = 0; dt < 4; ++dt)
#pragma unroll
          for (int r = 0; r < 4; ++r) Ot[dt][r] = 0.f;
        l_ = 0.f;
      }
    }
    __syncthreads();  // vmcnt(0): t+1 landed; all reads of buf[cur] done
    cur ^= 1;
  }
}

// ---------------------------------------------------------------- launch
extern "C" void kernel_launch(void* const* d_in, const int* in_sizes, int n_in,
                              void* d_out, int out_size, void* d_ws,
                              size_t ws_size, hipStream_t stream) {
  (void)in_sizes; (void)n_in; (void)out_size; (void)ws_size;
  const void* x       = d_in[0];
  const void* w_attn  = d_in[3];
  const void* w_aproj = d_in[5];
  const void* w_fc    = d_in[9];
  const void* w_mproj = d_in[11];

  char* ws = (char*)d_ws;
  ushortT* h1  = (ushortT*)(ws);                 // [8192,768] bf16; later vt
  ushortT* qkv = (ushortT*)(ws + 12582912);      // [8192,2304] bf16
  ushortT* yb  = (ushortT*)(ws + 50331648);      // [8192,768] bf16; later h2
  float*   x1  = (float*)(ws + 62914560);        // [8192,768] fp32
  ushortT* fcg = (ushortT*)(ws + 88080384);      // [8192,3072] bf16
  ushortT* wT0 = (ushortT*)(ws + 138412032);     // w_attn^T  [2304,768]
  ushortT* wT1 = (ushortT*)(ws + 141950976);     // w_aproj^T [768,768]
  ushortT* wT2 = (ushortT*)(ws + 143130624);     // w_fc^T    [3072,768]
  ushortT* wT3 = (ushortT*)(ws + 147849216);     // w_mproj^T [768,3072]
  ushortT* pv  = (ushortT*)(ws + 152567808);     // packed vectors (bf16)
  int*     flag = (int*)(ws + 152600576);
  ushortT* vt  = h1;   // [48][64][2048] bf16, h1 dead after qkv GEMM
  ushortT* h2  = yb;   // yb dead after aproj GEMM

  const int O_LN1G = 0, O_LN1B = 768, O_BATT = 1536, O_BAPR = 3840,
            O_LN2G = 4608, O_LN2B = 5376, O_BFC = 6144, O_BMPR = 9216;

  detect_dtype<<<1, 256, 0, stream>>>((const ushortT*)w_fc, flag);

  VecArgs va;
  va.src[0] = d_in[1];  va.n[0] = 768;  va.dstoff[0] = O_LN1G;
  va.src[1] = d_in[2];  va.n[1] = 768;  va.dstoff[1] = O_LN1B;
  va.src[2] = d_in[4];  va.n[2] = 2304; va.dstoff[2] = O_BATT;
  va.src[3] = d_in[6];  va.n[3] = 768;  va.dstoff[3] = O_BAPR;
  va.src[4] = d_in[7];  va.n[4] = 768;  va.dstoff[4] = O_LN2G;
  va.src[5] = d_in[8];  va.n[5] = 768;  va.dstoff[5] = O_LN2B;
  va.src[6] = d_in[10]; va.n[6] = 3072; va.dstoff[6] = O_BFC;
  va.src[7] = d_in[12]; va.n[7] = 768;  va.dstoff[7] = O_BMPR;
  convert_vecs<<<dim3(12, 8), 256, 0, stream>>>(va, pv, flag);

  dim3 tb(32, 8);
  transpose_any<<<dim3(72, 24), tb, 0, stream>>>(w_attn, wT0, 768, 2304, flag);
  transpose_any<<<dim3(24, 24), tb, 0, stream>>>(w_aproj, wT1, 768, 768, flag);
  transpose_any<<<dim3(96, 24), tb, 0, stream>>>(w_fc, wT2, 768, 3072, flag);
  transpose_any<<<dim3(24, 96), tb, 0, stream>>>(w_mproj, wT3, 3072, 768, flag);

  ln_kernel<0><<<8192, 256, 0, stream>>>(x, pv + O_LN1G, pv + O_LN1B, h1, flag);
  // qkv: M=8192 (nbm=64), N=2304 (nbn=18) -> 1152 blocks
  gemm_sb<0><<<1152, 256, 0, stream>>>(
      h1, wT0, pv + O_BATT, nullptr, qkv, 2304, 768, 64, 18, flag);
  vtrans_kernel<<<dim3(32, 48), 256, 0, stream>>>(qkv, vt);
  attn_kernel<<<dim3(16, 48), 256, 0, stream>>>(qkv, vt, yb);
  // aproj: nbm=64, nbn=6 -> 384 blocks
  gemm_sb<2><<<384, 256, 0, stream>>>(
      yb, wT1, pv + O_BAPR, x, x1, 768, 768, 64, 6, flag);
  ln_kernel<1><<<8192, 256, 0, stream>>>(x1, pv + O_LN2G, pv + O_LN2B, h2, flag);
  // fc: nbm=64, nbn=24 -> 1536 blocks
  gemm_sb<1><<<1536, 256, 0, stream>>>(
      h2, wT2, pv + O_BFC, nullptr, fcg, 3072, 768, 64, 24, flag);
  // mproj: nbm=64, nbn=6 -> 384 blocks, K=3072
  gemm_sb<3><<<384, 256, 0, stream>>>(
      fcg, wT3, pv + O_BMPR, x1, d_out, 768, 3072, 64, 6, flag);
}

// Round 5
// 419.082 us; speedup vs baseline: 1.0452x; 1.0452x over previous
//
#include <hip/hip_runtime.h>

// GPT-2 block forward, MI355X/gfx950. B=4 T=2048 C=768 H=12 D=64; M=8192.
// R14: GEMM = m201-style fine-phase pipeline adapted to small-N shapes:
//   - BM=128, BK=32, 256 thr / 4 waves. BN=256 (qkv,fc): wave grid 1x4,
//     per-wave 128x64 (8x4 frags -> 24 ds_read per 64 MFMA, MFMA-bound).
//     BN=128 (aproj,mproj): 2x2 grid, 64x64/wave, 384 blocks (all CUs).
//   - 3-slot LDS ring (72/48 KiB -> 2-3 blocks/CU), stage t+2 during t,
//     counted end-of-tile vmcnt(6)/(4), never drain-0 in loop (T3+T4).
//   - per-K-tile fine phases {8 ds_read || 3 glds16 -> bar -> setprio
//     16 MFMA -> bar}; swizzle: stored slot = logical ^ ((row>>1)&3),
//     pre-swizzled glds16 source + same XOR on ds_read (2-way max, free).
// Attention: R11 (glds16 double-buffered K/V staging, 1 barrier/tile).

typedef unsigned short ushortT;
typedef unsigned int uintT;
typedef __attribute__((ext_vector_type(8))) __bf16 bf16x8;
typedef __attribute__((ext_vector_type(4))) float f32x4;

#define MFMA16(a, b, c) __builtin_amdgcn_mfma_f32_16x16x32_bf16(a, b, c, 0, 0, 0)

__device__ inline float b2f(ushortT u) {
  return __uint_as_float(((uintT)u) << 16);
}
__device__ inline ushortT f2b(float f) {  // round-to-nearest-even
  uintT x = __float_as_uint(f);
  uintT r = x + 0x7fffu + ((x >> 16) & 1u);
  return (ushortT)(r >> 16);
}
// pack two f32 -> two bf16 (RTZ) in one v_perm_b32
__device__ inline uintT pack_bf2(float a, float b) {
  return __builtin_amdgcn_perm(__float_as_uint(b), __float_as_uint(a),
                               0x07060302u);
}

__device__ inline float fast_exp2(float x) {
#if __has_builtin(__builtin_amdgcn_exp2f)
  return __builtin_amdgcn_exp2f(x);
#else
  return exp2f(x);
#endif
}

__device__ inline float gelu_tanh(float v) {
  float t = 0.7978845608028654f * (v + 0.044715f * v * v * v);
  return v / (1.0f + __expf(-2.0f * t));
}

// async 16B/lane global->LDS. LDS dest = wave-uniform base + lane*16.
__device__ __forceinline__ void glds16(const ushortT* g, ushortT* l) {
  __builtin_amdgcn_global_load_lds(
      (const __attribute__((address_space(1))) unsigned int*)(const void*)g,
      (__attribute__((address_space(3))) unsigned int*)(void*)l, 16, 0, 0);
}

// ------------------------------------------------------------- dtype detect
__global__ __launch_bounds__(256) void detect_dtype(
    const ushortT* __restrict__ w, int* __restrict__ flag) {
  __shared__ int red;
  if (threadIdx.x == 0) red = 0;
  __syncthreads();
  int crazy = 0;
  for (int i = threadIdx.x; i < 4096; i += 256) {
    uintT e = (w[2 * i] >> 7) & 0xFF;
    if (e >= 150) crazy = 1;
  }
  if (crazy) atomicOr(&red, 1);
  __syncthreads();
  if (threadIdx.x == 0) *flag = red;
}

// ------------------------------------------------------------- small vectors
struct VecArgs {
  const void* src[8];
  int n[8];
  int dstoff[8];
};
__global__ __launch_bounds__(256) void convert_vecs(
    VecArgs a, ushortT* __restrict__ pv, const int* __restrict__ flag) {
  int fl = *flag;
  int t = blockIdx.y;
  int i = blockIdx.x * 256 + threadIdx.x;
  if (i >= a.n[t]) return;
  float v = fl ? ((const float*)a.src[t])[i] : b2f(((const ushortT*)a.src[t])[i]);
  pv[a.dstoff[t] + i] = f2b(v);
}

// ---------------------------------------------------------------- transpose
__global__ __launch_bounds__(256) void transpose_any(
    const void* __restrict__ in, ushortT* __restrict__ out, int K, int N,
    const int* __restrict__ flag) {
  __shared__ ushortT t[32][33];
  int fl = *flag;
  int n0 = blockIdx.x * 32, k0 = blockIdx.y * 32;
  int x = threadIdx.x, y0 = threadIdx.y;
#pragma unroll
  for (int i = y0; i < 32; i += 8) {
    size_t idx = (size_t)(k0 + i) * N + n0 + x;
    t[i][x] = fl ? f2b(((const float*)in)[idx]) : ((const ushortT*)in)[idx];
  }
  __syncthreads();
#pragma unroll
  for (int i = y0; i < 32; i += 8)
    out[(size_t)(n0 + i) * K + k0 + x] = t[x][i];
}

// ------------------------------------------------------- V transpose (attn)
__global__ __launch_bounds__(256) void vtrans_kernel(
    const ushortT* __restrict__ qkv, ushortT* __restrict__ vt) {
  const int T = 2048, C3 = 2304;
  __shared__ ushortT tile[64][65];
  int bh = blockIdx.y;
  int b = bh / 12, h = bh % 12;
  int t0 = blockIdx.x * 64;
  int col = threadIdx.x & 63, rowi = threadIdx.x >> 6;
#pragma unroll
  for (int rr = rowi; rr < 64; rr += 4)
    tile[rr][col] =
        qkv[((size_t)(b * T + t0 + rr)) * C3 + 1536 + h * 64 + col];
  __syncthreads();
#pragma unroll
  for (int dd = rowi; dd < 64; dd += 4)
    vt[((size_t)bh * 64 + dd) * T + t0 + col] = tile[col][dd];
}

// ---------------------------------------------------------------- layernorm
template <int MODE>
__global__ __launch_bounds__(256) void ln_kernel(
    const void* __restrict__ xin, const ushortT* __restrict__ g,
    const ushortT* __restrict__ bb, ushortT* __restrict__ out,
    const int* __restrict__ flag) {
  const int C = 768;
  bool f32;
  if constexpr (MODE == 1) f32 = true; else f32 = (*flag != 0);
  size_t base = (size_t)blockIdx.x * C;
  int tid = threadIdx.x;
  const float* xf = (const float*)xin;
  const ushortT* xb = (const ushortT*)xin;
  float v0 = f32 ? xf[base + tid]       : b2f(xb[base + tid]);
  float v1 = f32 ? xf[base + tid + 256] : b2f(xb[base + tid + 256]);
  float v2 = f32 ? xf[base + tid + 512] : b2f(xb[base + tid + 512]);
  float s = v0 + v1 + v2;
  float q = v0 * v0 + v1 * v1 + v2 * v2;
#pragma unroll
  for (int off = 32; off; off >>= 1) {
    s += __shfl_xor(s, off);
    q += __shfl_xor(q, off);
  }
  __shared__ float as_[4], aq_[4];
  if ((tid & 63) == 0) { as_[tid >> 6] = s; aq_[tid >> 6] = q; }
  __syncthreads();
  s = as_[0] + as_[1] + as_[2] + as_[3];
  q = aq_[0] + aq_[1] + aq_[2] + aq_[3];
  float mu = s * (1.0f / 768.0f);
  float var = q * (1.0f / 768.0f) - mu * mu;
  float rs = rsqrtf(var + 1e-5f);
  ushortT* orow = out + base;
  orow[tid]       = f2b((v0 - mu) * rs * b2f(g[tid])       + b2f(bb[tid]));
  orow[tid + 256] = f2b((v1 - mu) * rs * b2f(g[tid + 256]) + b2f(bb[tid + 256]));
  orow[tid + 512] = f2b((v2 - mu) * rs * b2f(g[tid + 512]) + b2f(bb[tid + 512]));
}

// ---------------------------------------------------------------- GEMM
// C[M,N] = A[M,K] @ Bt[N,K]^T + bias. BM=128, BK=32, 256 thr (4 waves).
// BN=256: wave grid 1x4 (per-wave 128x64, MI=8,NI=4), 2 phases/K-tile.
// BN=128: wave grid 2x2 (per-wave 64x64,  MI=4,NI=4), 1 phase/K-tile.
// 3-slot LDS ring; stage tile t+2 during t; counted end-of-tile vmcnt.
// LDS rows = 32 elems (64B); stored 16B-slot s holds logical slot
// s ^ ((row>>1)&3) (pre-swizzled global source; same XOR on ds_read).
// EPI: 0 bias->bf16 | 1 bias+gelu->bf16 | 2 bias+res(flag dtype)->fp32
//      3 bias+res(fp32)->flag-dtype out
template <int EPI, int BN>
__global__ __launch_bounds__(256, 2) void gemm_8p(
    const ushortT* __restrict__ A, const ushortT* __restrict__ Bt,
    const ushortT* __restrict__ bias, const void* __restrict__ res,
    void* __restrict__ out, int N, int K, int nbm, int nbn,
    const int* __restrict__ flag) {
  constexpr int MI = (BN == 256) ? 8 : 4;
  constexpr int NI = 4;
  constexpr int LOADS = 2 + BN / 64;  // glds16 per thread per K-tile
  __shared__ ushortT As3[3][128 * 32];
  __shared__ ushortT Bs3[3][BN * 32];
  int fl = (EPI >= 2) ? *flag : 0;
  int tid = threadIdx.x;
  int lane = tid & 63, wave = tid >> 6;
  int quad = lane >> 4, n = lane & 15;
  // per-wave output origin within the tile
  int wm, wn;
  if constexpr (BN == 256) { wm = 0; wn = wave * 64; }
  else { wm = (wave >> 1) * 64; wn = (wave & 1) * 64; }
  // XCD-locality decode: all nbn n-blocks of one m-strip land on one XCD
  int l = blockIdx.x;
  int xcd = l & 7, j = l >> 3;
  int m0 = (xcd * (nbm >> 3) + j / nbn) * 128;
  int n0 = (j % nbn) * BN;

  // staging map: thread -> row tid>>2 (of 64-row sweep), 16B slot tid&3;
  // source col pre-swizzled (involution) so LDS dest stays linear.
  int trow = tid >> 2;
  int tc = (((tid & 3) ^ ((trow >> 1) & 3)) << 3);
  const ushortT* ga = A + (size_t)(m0 + trow) * K + tc;
  const ushortT* gb = Bt + (size_t)(n0 + trow) * K + tc;

  // ds_read swizzled 16B slot: quad ^ ((n>>1)&3) (row bases are mult of 16)
  const int cs = (quad ^ ((n >> 1) & 3)) << 3;

  int kt = K >> 5;
  f32x4 acc[MI][NI] = {};

  auto stage = [&](int tt, int slot) {
    int k0 = tt << 5;
    ushortT* la = &As3[slot][0] + wave * 512;
    ushortT* lb = &Bs3[slot][0] + wave * 512;
    glds16(ga + k0, la);
    glds16(ga + (size_t)64 * K + k0, la + 2048);
    glds16(gb + k0, lb);
    glds16(gb + (size_t)64 * K + k0, lb + 2048);
    if constexpr (BN == 256) {
      glds16(gb + (size_t)128 * K + k0, lb + 4096);
      glds16(gb + (size_t)192 * K + k0, lb + 6144);
    }
  };

  // prologue: tiles 0,1 in flight; wait tile 0 (LOADS newest allowed out)
  stage(0, 0);
  stage(1, 1);
  if constexpr (BN == 256)
    asm volatile("s_waitcnt vmcnt(6)" ::: "memory");
  else
    asm volatile("s_waitcnt vmcnt(4)" ::: "memory");
  __builtin_amdgcn_s_barrier();

  int cur = 0;
  for (int t = 0; t < kt; ++t) {
    const ushortT* ca = &As3[cur][0];
    const ushortT* cb = &Bs3[cur][0];
    int nxt = cur + 2; if (nxt >= 3) nxt -= 3;
    bool pf = (t + 2) < kt;
    int pk0 = (t + 2) << 5;
    ushortT* la = &As3[nxt][0] + wave * 512;
    ushortT* lb = &Bs3[nxt][0] + wave * 512;

    bf16x8 af[4], bfr[NI];
    // ---- phase 0: af rows [wm..wm+63], all B frags; stage part 1
#pragma unroll
    for (int i = 0; i < 4; ++i)
      af[i] = *(const bf16x8*)(ca + (wm + i * 16 + n) * 32 + cs);
#pragma unroll
    for (int i = 0; i < NI; ++i)
      bfr[i] = *(const bf16x8*)(cb + (wn + i * 16 + n) * 32 + cs);
    if (pf) {
      glds16(ga + pk0, la);
      glds16(ga + (size_t)64 * K + pk0, la + 2048);
      glds16(gb + pk0, lb);
      if constexpr (BN == 128) glds16(gb + (size_t)64 * K + pk0, lb + 2048);
    }
    __builtin_amdgcn_s_barrier();
    __builtin_amdgcn_s_setprio(1);
#pragma unroll
    for (int mi = 0; mi < 4; ++mi)
#pragma unroll
      for (int ni = 0; ni < NI; ++ni)
        acc[mi][ni] = MFMA16(af[mi], bfr[ni], acc[mi][ni]);
    __builtin_amdgcn_s_setprio(0);
    if constexpr (BN == 256) {
      __builtin_amdgcn_s_barrier();
      // ---- phase 1: af rows [64..127]; stage part 2
#pragma unroll
      for (int i = 0; i < 4; ++i)
        af[i] = *(const bf16x8*)(ca + (64 + i * 16 + n) * 32 + cs);
      if (pf) {
        glds16(gb + (size_t)64 * K + pk0, lb + 2048);
        glds16(gb + (size_t)128 * K + pk0, lb + 4096);
        glds16(gb + (size_t)192 * K + pk0, lb + 6144);
      }
      __builtin_amdgcn_s_barrier();
      __builtin_amdgcn_s_setprio(1);
#pragma unroll
      for (int mi = 0; mi < 4; ++mi)
#pragma unroll
        for (int ni = 0; ni < NI; ++ni)
          acc[4 + mi][ni] = MFMA16(af[mi], bfr[ni], acc[4 + mi][ni]);
      __builtin_amdgcn_s_setprio(0);
    }
    // end-of-tile: tile t+1 must be landed; t+2's LOADS may stay in flight.
    if (pf) {
      if constexpr (BN == 256)
        asm volatile("s_waitcnt vmcnt(6)" ::: "memory");
      else
        asm volatile("s_waitcnt vmcnt(4)" ::: "memory");
    } else {
      asm volatile("s_waitcnt vmcnt(0)" ::: "memory");
    }
    __builtin_amdgcn_s_barrier();

    cur = cur + 1; if (cur == 3) cur = 0;
  }

  // ---- epilogue
#pragma unroll
  for (int mi = 0; mi < MI; ++mi) {
#pragma unroll
    for (int ni = 0; ni < NI; ++ni) {
      int gc = n0 + wn + ni * 16 + n;
      float bv = b2f(bias[gc]);
      int gr0 = m0 + wm + mi * 16 + quad * 4;
#pragma unroll
      for (int r = 0; r < 4; ++r) {
        size_t idx = (size_t)(gr0 + r) * N + gc;
        float v = acc[mi][ni][r] + bv;
        if constexpr (EPI == 1) v = gelu_tanh(v);
        if constexpr (EPI == 2) {
          v += fl ? ((const float*)res)[idx] : b2f(((const ushortT*)res)[idx]);
          ((float*)out)[idx] = v;
        } else if constexpr (EPI == 3) {
          v += ((const float*)res)[idx];
          if (fl) ((float*)out)[idx] = v;
          else    ((ushortT*)out)[idx] = f2b(v);
        } else {
          ((ushortT*)out)[idx] = f2b(v);
        }
      }
    }
  }
}

// ---------------------------------------------------------------- attention
// Flash, causal, balanced (block pj does q-tiles pj and 31-pj = 33 k-tiles).
// 4 waves x 16 q-rows. S^T = K Q^T, O^T = V^T P^T. Fixed-offset base-2
// softmax. K/V staged via global_load_lds DMA into a double buffer with
// XOR-swizzled source cols (linear LDS dest); one __syncthreads per tile.
__global__ __launch_bounds__(256) void attn_kernel(
    const ushortT* __restrict__ qkv, const ushortT* __restrict__ vt,
    ushortT* __restrict__ y) {
  const int T = 2048, C3 = 2304;
  constexpr int LDP = 72;
  __shared__ ushortT Ks[2][64 * 64];
  __shared__ ushortT Vs[2][64 * 64];
  __shared__ ushortT Ps[4 * 16 * LDP];
  int bh = blockIdx.y;
  int b = bh / 12, h = bh % 12;
  int pj = blockIdx.x;  // 0..15
  int tid = threadIdx.x;
  int lane = tid & 63, wave = tid >> 6;
  int quad = lane >> 4, n = lane & 15, n7 = n & 7;

  const ushortT* base = qkv + (size_t)b * T * C3;
  const ushortT* kbase = base + 768 + h * 64;
  const ushortT* vbase = vt + (size_t)bh * 64 * T;
  ushortT* myP = Ps + wave * 16 * LDP;

  const float QS = 0.18033688011112042f;  // log2(e)/8
  const float MB = 20.0f;                 // fixed base-2 shift

  int qtA = pj, qtB = 31 - pj;
  int nA = qtA + 1, ntot = 33;

  int srow = lane >> 3, scol = lane & 7;
  const ushortT* kg =
      kbase + (size_t)(wave * 16 + srow) * C3 + ((scol ^ srow) << 3);
  const ushortT* vg =
      vbase + (size_t)(wave * 16 + srow) * T + ((scol ^ srow) << 3);

  const int c0 = (quad ^ n7) << 3;
  const int c1 = ((4 + quad) ^ n7) << 3;

  int qt = qtA;
  int qw = qt * 64 + wave * 16;
  bf16x8 aq[2];
  {
    const ushortT* qrow = base + (size_t)(qw + n) * C3 + h * 64 + quad * 8;
#pragma unroll
    for (int dh = 0; dh < 2; ++dh) {
      union { ushortT u[8]; bf16x8 v; } tmp;
#pragma unroll
      for (int j = 0; j < 8; ++j) tmp.u[j] = f2b(b2f(qrow[dh * 32 + j]) * QS);
      aq[dh] = tmp.v;
    }
  }
  f32x4 Ot[4] = {};
  float l_ = 0.f;

  auto stage = [&](int kt_, int buf) {
    int kof = kt_ << 6;
    ushortT* lk = &Ks[buf][0] + wave * 1024;
    ushortT* lv = &Vs[buf][0] + wave * 1024;
    glds16(kg + (size_t)kof * C3, lk);
    glds16(kg + (size_t)(kof + 8) * C3, lk + 512);
    glds16(vg + kof, lv);
    glds16(vg + (size_t)8 * T + kof, lv + 512);
  };

  stage(0, 0);
  __syncthreads();  // emits vmcnt(0): tile 0 landed

  int cur = 0;
  for (int t = 0; t < ntot; ++t) {
    int kt = (t < nA) ? t : t - nA;
    if (t + 1 < ntot) {
      int ktn = (t + 1 < nA) ? t + 1 : t + 1 - nA;
      stage(ktn, cur ^ 1);  // prefetch t+1 while computing t
    }
    const ushortT* ks = &Ks[cur][0];
    const ushortT* vs = &Vs[cur][0];

    // ---- S^T = K (Q*QS)^T  (base-2 units)
    f32x4 St[4];
#pragma unroll
    for (int g = 0; g < 4; ++g) {
      bf16x8 ka0 = *(const bf16x8*)(ks + (g * 16 + n) * 64 + c0);
      bf16x8 ka1 = *(const bf16x8*)(ks + (g * 16 + n) * 64 + c1);
      f32x4 z = {};
      z = MFMA16(ka0, aq[0], z);
      St[g] = MFMA16(ka1, aq[1], z);
    }
    // ---- diagonal-tile causal mask
    if (kt == qt) {
      int lim = wave * 16 + n;
#pragma unroll
      for (int g = 0; g < 4; ++g)
#pragma unroll
        for (int r = 0; r < 4; ++r)
          if (g * 16 + quad * 4 + r > lim) St[g][r] = -1e30f;
    }
    // ---- fixed-offset exp2, accumulate l
    float ls = 0.f;
#pragma unroll
    for (int g = 0; g < 4; ++g) {
      float p0 = fast_exp2(St[g][0] - MB);
      float p1 = fast_exp2(St[g][1] - MB);
      float p2 = fast_exp2(St[g][2] - MB);
      float p3 = fast_exp2(St[g][3] - MB);
      ls += (p0 + p1) + (p2 + p3);
      uint2 pk;
      pk.x = pack_bf2(p0, p1);
      pk.y = pack_bf2(p2, p3);
      *(uint2*)(myP + n * LDP + g * 16 + quad * 4) = pk;
    }
    ls += __shfl_xor(ls, 16);
    ls += __shfl_xor(ls, 32);
    l_ += ls;

    // ---- O^T += V^T P^T
    bf16x8 pb0 = *(const bf16x8*)(myP + n * LDP + quad * 8);
    bf16x8 pb1 = *(const bf16x8*)(myP + n * LDP + 32 + quad * 8);
#pragma unroll
    for (int dt = 0; dt < 4; ++dt) {
      bf16x8 va0 = *(const bf16x8*)(vs + (dt * 16 + n) * 64 + c0);
      bf16x8 va1 = *(const bf16x8*)(vs + (dt * 16 + n) * 64 + c1);
      Ot[dt] = MFMA16(va0, pb0, Ot[dt]);
      Ot[dt] = MFMA16(va1, pb1, Ot[dt]);
    }

    // ---- phase end: epilogue + reset for phase B
    if (kt == qt) {
      float inv = 1.0f / l_;
      int qg = qw + n;
#pragma unroll
      for (int dt = 0; dt < 4; ++dt) {
        uint2 o;
        o.x = pack_bf2(Ot[dt][0] * inv, Ot[dt][1] * inv);
        o.y = pack_bf2(Ot[dt][2] * inv, Ot[dt][3] * inv);
        *(uint2*)(y + (size_t)(b * T + qg) * 768 + h * 64 + dt * 16 +
                  quad * 4) = o;
      }
      if (t + 1 < ntot) {
        qt = qtB;
        qw = qt * 64 + wave * 16;
        const ushortT* qrow =
            base + (size_t)(qw + n) * C3 + h * 64 + quad * 8;
#pragma unroll
        for (int dh = 0; dh < 2; ++dh) {
          union { ushortT u[8]; bf16x8 v; } tmp;
#pragma unroll
          for (int j = 0; j < 8; ++j)
            tmp.u[j] = f2b(b2f(qrow[dh * 32 + j]) * QS);
          aq[dh] = tmp.v;
        }
#pragma unroll
        for (int dt = 0; dt < 4; ++dt)
#pragma unroll
          for (int r = 0; r < 4; ++r) Ot[dt][r] = 0.f;
        l_ = 0.f;
      }
    }
    __syncthreads();  // vmcnt(0): t+1 landed; all reads of buf[cur] done
    cur ^= 1;
  }
}

// ---------------------------------------------------------------- launch
extern "C" void kernel_launch(void* const* d_in, const int* in_sizes, int n_in,
                              void* d_out, int out_size, void* d_ws,
                              size_t ws_size, hipStream_t stream) {
  (void)in_sizes; (void)n_in; (void)out_size; (void)ws_size;
  const void* x       = d_in[0];
  const void* w_attn  = d_in[3];
  const void* w_aproj = d_in[5];
  const void* w_fc    = d_in[9];
  const void* w_mproj = d_in[11];

  char* ws = (char*)d_ws;
  ushortT* h1  = (ushortT*)(ws);                 // [8192,768] bf16; later vt
  ushortT* qkv = (ushortT*)(ws + 12582912);      // [8192,2304] bf16
  ushortT* yb  = (ushortT*)(ws + 50331648);      // [8192,768] bf16; later h2
  float*   x1  = (float*)(ws + 62914560);        // [8192,768] fp32
  ushortT* fcg = (ushortT*)(ws + 88080384);      // [8192,3072] bf16
  ushortT* wT0 = (ushortT*)(ws + 138412032);     // w_attn^T  [2304,768]
  ushortT* wT1 = (ushortT*)(ws + 141950976);     // w_aproj^T [768,768]
  ushortT* wT2 = (ushortT*)(ws + 143130624);     // w_fc^T    [3072,768]
  ushortT* wT3 = (ushortT*)(ws + 147849216);     // w_mproj^T [768,3072]
  ushortT* pv  = (ushortT*)(ws + 152567808);     // packed vectors (bf16)
  int*     flag = (int*)(ws + 152600576);
  ushortT* vt  = h1;   // [48][64][2048] bf16, h1 dead after qkv GEMM
  ushortT* h2  = yb;   // yb dead after aproj GEMM

  const int O_LN1G = 0, O_LN1B = 768, O_BATT = 1536, O_BAPR = 3840,
            O_LN2G = 4608, O_LN2B = 5376, O_BFC = 6144, O_BMPR = 9216;

  detect_dtype<<<1, 256, 0, stream>>>((const ushortT*)w_fc, flag);

  VecArgs va;
  va.src[0] = d_in[1];  va.n[0] = 768;  va.dstoff[0] = O_LN1G;
  va.src[1] = d_in[2];  va.n[1] = 768;  va.dstoff[1] = O_LN1B;
  va.src[2] = d_in[4];  va.n[2] = 2304; va.dstoff[2] = O_BATT;
  va.src[3] = d_in[6];  va.n[3] = 768;  va.dstoff[3] = O_BAPR;
  va.src[4] = d_in[7];  va.n[4] = 768;  va.dstoff[4] = O_LN2G;
  va.src[5] = d_in[8];  va.n[5] = 768;  va.dstoff[5] = O_LN2B;
  va.src[6] = d_in[10]; va.n[6] = 3072; va.dstoff[6] = O_BFC;
  va.src[7] = d_in[12]; va.n[7] = 768;  va.dstoff[7] = O_BMPR;
  convert_vecs<<<dim3(12, 8), 256, 0, stream>>>(va, pv, flag);

  dim3 tb(32, 8);
  transpose_any<<<dim3(72, 24), tb, 0, stream>>>(w_attn, wT0, 768, 2304, flag);
  transpose_any<<<dim3(24, 24), tb, 0, stream>>>(w_aproj, wT1, 768, 768, flag);
  transpose_any<<<dim3(96, 24), tb, 0, stream>>>(w_fc, wT2, 768, 3072, flag);
  transpose_any<<<dim3(24, 96), tb, 0, stream>>>(w_mproj, wT3, 3072, 768, flag);

  ln_kernel<0><<<8192, 256, 0, stream>>>(x, pv + O_LN1G, pv + O_LN1B, h1, flag);
  // qkv: nbm=64, BN=256 -> nbn=9 -> 576 blocks
  gemm_8p<0, 256><<<576, 256, 0, stream>>>(
      h1, wT0, pv + O_BATT, nullptr, qkv, 2304, 768, 64, 9, flag);
  vtrans_kernel<<<dim3(32, 48), 256, 0, stream>>>(qkv, vt);
  attn_kernel<<<dim3(16, 48), 256, 0, stream>>>(qkv, vt, yb);
  // aproj: nbm=64, BN=128 -> nbn=6 -> 384 blocks
  gemm_8p<2, 128><<<384, 256, 0, stream>>>(
      yb, wT1, pv + O_BAPR, x, x1, 768, 768, 64, 6, flag);
  ln_kernel<1><<<8192, 256, 0, stream>>>(x1, pv + O_LN2G, pv + O_LN2B, h2, flag);
  // fc: nbm=64, BN=256 -> nbn=12 -> 768 blocks
  gemm_8p<1, 256><<<768, 256, 0, stream>>>(
      h2, wT2, pv + O_BFC, nullptr, fcg, 3072, 768, 64, 12, flag);
  // mproj: nbm=64, BN=128 -> nbn=6 -> 384 blocks, K=3072
  gemm_8p<3, 128><<<384, 256, 0, stream>>>(
      fcg, wT3, pv + O_BMPR, x1, d_out, 768, 3072, 64, 6, flag);
}